// Round 12
// baseline (379.134 us; speedup 1.0000x reference)
//
#include <hip/hip_runtime.h>

namespace {
constexpr int B = 16;
constexpr int N = 900;   // queries (columns)
constexpr int NP = 960;  // padded cost-row stride (floats)
constexpr int T = 64;    // targets (rows)
constexpr int L = 96;
constexpr int CACHE = 40;  // rows cached in LDS: 40*960*4 = 153,600 B
constexpr float BIGF = 1e9f;
}

// Faithful reproduction of the reference cost, FP-contract off to match numpy
__device__ __forceinline__ float cost_elem(float cx, float cy, float w, float h,
                                           float prob,
                                           float tx0, float ty0, float tx1, float ty1) {
#pragma clang fp contract(off)
  float hw = w * 0.5f, hh = h * 0.5f;
  float x0 = cx - hw, y0 = cy - hh;
  float x1 = cx + hw, y1 = cy + hh;
  float cb = fabsf(cx - tx0);
  cb = cb + fabsf(cy - ty0);
  cb = cb + fabsf(w - tx1);
  cb = cb + fabsf(h - ty1);
  float area1 = (x1 - x0) * (y1 - y0);
  float area2 = (tx1 - tx0) * (ty1 - ty0);
  float iw = fmaxf(fminf(x1, tx1) - fmaxf(x0, tx0), 0.0f);
  float ih = fmaxf(fminf(y1, ty1) - fmaxf(y0, ty0), 0.0f);
  float inter = iw * ih;
  float uni = (area1 + area2) - inter;
  float iou = inter / uni;
  float ew = fmaxf(fmaxf(x1, tx1) - fminf(x0, tx0), 0.0f);
  float eh = fmaxf(fmaxf(y1, ty1) - fminf(y0, ty0), 0.0f);
  float ae = ew * eh;
  float giou = iou - (ae - uni) / ae;
  float c = cb * 5.0f;
  c = c + giou * (-2.0f);
  c = c - prob;
  return c;
}

// Covers padded columns [900,960) with BIGF so the solver needs no bounds masks.
__global__ __launch_bounds__(256) void cost_kernel(const float* __restrict__ outputs,
                                                   const float* __restrict__ targets,
                                                   float* __restrict__ cost) {
  __shared__ float tb[T * 4];
  __shared__ int tc[T];
  int b = blockIdx.y;
  int tid = threadIdx.x;
  if (tid < T) {
    const float* tr = targets + (size_t)(b * T + tid) * 5;
    tb[tid * 4 + 0] = tr[0];
    tb[tid * 4 + 1] = tr[1];
    tb[tid * 4 + 2] = tr[2];
    tb[tid * 4 + 3] = tr[3];
    tc[tid] = (int)tr[4];
  }
  __syncthreads();
  int n = blockIdx.x * 256 + tid;
  if (n >= NP) return;
  float* cbase = cost + (size_t)b * T * NP + n;
  if (n >= N) {
    for (int t = 0; t < T; ++t) cbase[(size_t)t * NP] = BIGF;
    return;
  }
  const float* orow = outputs + (size_t)(b * N + n) * L;
  float4 box = *reinterpret_cast<const float4*>(orow);
  for (int t = 0; t < T; ++t) {
    float pc = orow[5 + tc[t]];
    float c = cost_elem(box.x, box.y, box.z, box.w, pc,
                        tb[t * 4 + 0], tb[t * 4 + 1], tb[t * 4 + 2], tb[t * 4 + 3]);
    cbase[(size_t)t * NP] = c;
  }
}

// 64-bit lexicographic min step via DPP (hi = ordered float key, lo = packed j|way).
template <int CTRL>
__device__ __forceinline__ void dpp_step64(unsigned& hi, unsigned& lo) {
  unsigned h2 = (unsigned)__builtin_amdgcn_update_dpp((int)hi, (int)hi, CTRL, 0xf, 0xf, false);
  unsigned l2 = (unsigned)__builtin_amdgcn_update_dpp((int)lo, (int)lo, CTRL, 0xf, 0xf, false);
  unsigned long long a = ((unsigned long long)h2 << 32) | l2;
  unsigned long long cur = ((unsigned long long)hi << 32) | lo;
  bool take = a < cur;
  hi = take ? h2 : hi;
  lo = take ? l2 : lo;
}

__device__ __forceinline__ void wave_min64(unsigned& hi, unsigned& lo) {
  dpp_step64<0x111>(hi, lo);  // row_shr:1
  dpp_step64<0x112>(hi, lo);  // row_shr:2
  dpp_step64<0x114>(hi, lo);  // row_shr:4
  dpp_step64<0x118>(hi, lo);  // row_shr:8
  dpp_step64<0x142>(hi, lo);  // row_bcast:15
  dpp_step64<0x143>(hi, lo);  // row_bcast:31 -> lane 63 holds result
}

// One wave per batch. JV shortest-augmenting-path, bit-faithful to reference.
// Column mapping: 0-based col n0 = 256*k4 + 4*lane + cc, slot e = 4*k4+cc (j ascending in e).
template <bool PRECOMP>
__global__ __launch_bounds__(64) void hungarian_kernel(const float* __restrict__ outputs,
                                                       const float* __restrict__ targets,
                                                       const float* __restrict__ cost,
                                                       int* __restrict__ out) {
  __shared__ float row_cache[CACHE * NP];  // rows 0..CACHE-1, filled at their row-step
  __shared__ int p_lds[N + 1];
  __shared__ int qq[T];
  __shared__ float tb[T * 4];
  __shared__ int tc[T];

  int b = blockIdx.x;
  int lane = threadIdx.x;

  for (int j = lane; j <= N; j += 64) p_lds[j] = 0;
  if (!PRECOMP) {
    const float* tr = targets + (size_t)(b * T + lane) * 5;
    tb[lane * 4 + 0] = tr[0];
    tb[lane * 4 + 1] = tr[1];
    tb[lane * 4 + 2] = tr[2];
    tb[lane * 4 + 3] = tr[3];
    tc[lane] = (int)tr[4];
  }

  float u_reg = 0.0f;  // u[lane+1]
  float v[16], minv[16], uf[16];
  unsigned pk[16];
#pragma unroll
  for (int e = 0; e < 16; ++e) {
    v[e] = 0.0f;
    pk[e] = 0u;  // init once; stale pk can never win (its slot value stays ~BIGF)
  }

  const float* cost_b = PRECOMP ? (cost + (size_t)b * T * NP) : nullptr;
  const float* obase = outputs + (size_t)b * N * L;
  int lane12 = lane << 12;

  int idx4[4];  // clamped within-row float offsets (pads hold BIGF)
#pragma unroll
  for (int k4 = 0; k4 < 4; ++k4) {
    int idx = (k4 << 8) + (lane << 2);
    idx4[k4] = idx > (NP - 4) ? (NP - 4) : idx;
  }

  float4 c4[4];
  auto load_global = [&](int trow) {
    const float* crow = cost_b + (size_t)trow * NP;
#pragma unroll
    for (int k4 = 0; k4 < 4; ++k4)
      c4[k4] = *reinterpret_cast<const float4*>(crow + idx4[k4]);
  };
  auto load_cached = [&](int trow) {  // mid-path rows (<= i-2): cached if < CACHE
    if (trow < CACHE) {
      const float* crow = row_cache + trow * NP;
#pragma unroll
      for (int k4 = 0; k4 < 4; ++k4)
        c4[k4] = *reinterpret_cast<const float4*>(crow + idx4[k4]);
    } else {
      const float* crow = cost_b + (size_t)trow * NP;
#pragma unroll
      for (int k4 = 0; k4 < 4; ++k4)
        c4[k4] = *reinterpret_cast<const float4*>(crow + idx4[k4]);
    }
  };
  auto gen_row = [&](int trow) {  // !PRECOMP fallback: recompute costs into c4
    float tx0 = tb[trow * 4 + 0], ty0 = tb[trow * 4 + 1];
    float tx1 = tb[trow * 4 + 2], ty1 = tb[trow * 4 + 3];
    int cls = tc[trow];
#pragma unroll
    for (int k4 = 0; k4 < 4; ++k4) {
      float tmp[4];
#pragma unroll
      for (int cc = 0; cc < 4; ++cc) {
        int n0 = (k4 << 8) + (lane << 2) + cc;
        if (n0 < N) {
          const float* orow = obase + (size_t)n0 * L;
          float4 box = *reinterpret_cast<const float4*>(orow);
          float pc = orow[5 + cls];
          tmp[cc] = cost_elem(box.x, box.y, box.z, box.w, pc, tx0, ty0, tx1, ty1);
        } else {
          tmp[cc] = BIGF;
        }
      }
      c4[k4] = make_float4(tmp[0], tmp[1], tmp[2], tmp[3]);
    }
  };

  __syncthreads();
  if (PRECOMP) load_global(0); else gen_row(0);  // row 0 in flight for row-step 1

  for (int i = 1; i <= T; ++i) {
    // fill LDS cache with row i-1 (currently in c4) — off critical path
    if (PRECOMP && (i - 1) < CACHE) {
      float* crow = row_cache + (i - 1) * NP;
#pragma unroll
      for (int k4 = 0; k4 < 4; ++k4)
        *reinterpret_cast<float4*>(crow + idx4[k4]) = c4[k4];
    }
#pragma unroll
    for (int e = 0; e < 16; ++e) {
      minv[e] = BIGF;
      uf[e] = 0.0f;
    }
    int j0s = 0;
    float ui0 = __int_as_float(__builtin_amdgcn_readlane(__float_as_int(u_reg), i - 1));
    bool vis = (lane == i - 1);
    int rj = 0, rw = 0, rp = 0;  // per-lane iteration history (lane g = iteration g)

    for (int guard = 0; guard <= T + 3; ++guard) {
      // --- candidate scan: reference-exact cur for unused (uf=0); used pushed +BIGF ---
#pragma unroll
      for (int k4 = 0; k4 < 4; ++k4) {
#pragma unroll
        for (int cc = 0; cc < 4; ++cc) {
          int e = (k4 << 2) | cc;
          float cur = ((&c4[k4].x)[cc] - ui0) - v[e];
          cur = fmaf(uf[e], BIGF, cur);
          unsigned pknew = (unsigned)(lane12 + (((k4 << 8) + cc + 1) << 10)) | (unsigned)j0s;
          bool imp = cur < minv[e];
          minv[e] = imp ? cur : minv[e];
          pk[e] = imp ? pknew : pk[e];
        }
      }
      // --- depth-4 in-lane FLOAT tree: strict < keeps lower e on tie (= lower j,
      //     since column index ascends with e) — same selection as u64 lex tree ---
      float m_[16];
      unsigned q_[16];
#pragma unroll
      for (int e = 0; e < 16; ++e) {
        m_[e] = minv[e];
        q_[e] = pk[e];
      }
#pragma unroll
      for (int st = 1; st < 16; st <<= 1) {
#pragma unroll
        for (int e = 0; e < 16; e += (st << 1)) {
          bool t2 = m_[e + st] < m_[e];
          m_[e] = t2 ? m_[e + st] : m_[e];
          q_[e] = t2 ? q_[e + st] : q_[e];
        }
      }
      // keypack only the per-lane winner for the cross-lane u64 lex min
      int mi = __float_as_int(m_[0]);
      unsigned hi = (unsigned)(mi ^ ((mi >> 31) | 0x80000000));
      unsigned lo = q_[0];

      // per-lane gather of p[candidate] BEFORE the DPP chain (latency hides under it)
      int bj = (int)(lo >> 10);
      int bp_g = p_lds[bj <= N ? bj : N];

      wave_min64(hi, lo);
      unsigned khi = (unsigned)__builtin_amdgcn_readlane((int)hi, 63);
      unsigned klo = (unsigned)__builtin_amdgcn_readlane((int)lo, 63);
      int mbits = (khi & 0x80000000u) ? (int)(khi ^ 0x80000000u) : (int)(~khi);
      float delta = __int_as_float(mbits);
      int j1 = (int)(klo >> 10);
      int w1 = (int)(klo & 1023u);
      int jj = j1 - 1;
      int o1 = (jj >> 2) & 63;
      int e1 = ((jj >> 8) << 2) | (jj & 3);
      int p1 = __builtin_amdgcn_readlane(bp_g, o1);  // winner lane's gathered p[j1]

      if (p1 != 0) {  // next row's data in flight ASAP
        if (PRECOMP) load_cached(p1 - 1); else gen_row(p1 - 1);
      }

      // archive (j1, w1, p1) in lane `guard`'s registers (augment reads them back)
      if (lane == guard) { rj = j1; rw = w1; rp = p1; }

      // --- reference-exact potential updates (registers only, branchless) ---
      if (vis) u_reg += delta;
#pragma unroll
      for (int e = 0; e < 16; ++e) {
        minv[e] = fmaf(uf[e], delta, minv[e] - delta);  // unused: exact minv-delta
        v[e] = fmaf(uf[e], -delta, v[e]);               // used: exact v-delta
      }
      vis = vis || (lane == p1 - 1);

      // --- mark j1 used: pure cndmask, no branches ---
      {
        bool onlane = (lane == o1);
#pragma unroll
        for (int e = 0; e < 16; ++e) {
          bool hit = onlane && (e == e1);
          minv[e] = hit ? BIGF : minv[e];
          uf[e] = hit ? 1.0f : uf[e];
        }
      }

      // row p1 is not in this iteration's visited set -> u[p1] unchanged by the
      // update above; safe to read post-update.
      ui0 = __int_as_float(
          __builtin_amdgcn_readlane(__float_as_int(u_reg), p1 > 0 ? p1 - 1 : 0));
      j0s = j1;
      if (p1 == 0) break;
    }

    // prefetch next row-step's first row; hides under the augment walk
    if (i < T) {
      if (PRECOMP) load_global(i); else gen_row(i);
    }

    // augment via register history: p[jc] = (way==0) ? i : p_old[way[jc]]
    {
      int jc = j0s;
      for (int g2 = 0; g2 <= T + 1 && jc != 0; ++g2) {
        unsigned long long ma = __ballot(rj == jc);
        int a = (int)(__ffsll(ma) - 1);
        int w = __builtin_amdgcn_readlane(rw, a & 63);
        int pv;
        if (w == 0) {
          pv = i;
        } else {
          unsigned long long mb = __ballot(rj == w);
          int bl = (int)(__ffsll(mb) - 1);
          pv = __builtin_amdgcn_readlane(rp, bl & 63);
        }
        if (lane == 0) p_lds[jc] = pv;
        jc = w;
      }
    }
  }

  __syncthreads();
  // extract q: p[j] = row assigned to column j (1-indexed)
  for (int j = 1 + lane; j <= N; j += 64) {
    int r = p_lds[j];
    if (r > 0) qq[r - 1] = j - 1;
  }
  __syncthreads();
  // sort pairs by query index: rank of q_t among all q (distinct values)
  int qt = qq[lane];
  int rank = 0;
  for (int s = 0; s < T; ++s) rank += (qq[s] < qt) ? 1 : 0;
  out[b * T + rank] = qt;            // i_idx (sorted query indices)
  out[B * T + b * T + rank] = lane;  // j_idx (target per sorted position)
}

extern "C" void kernel_launch(void* const* d_in, const int* in_sizes, int n_in,
                              void* d_out, int out_size, void* d_ws, size_t ws_size,
                              hipStream_t stream) {
  const float* outputs = (const float*)d_in[0];
  const float* targets = (const float*)d_in[1];
  int* out = (int*)d_out;

  size_t cost_bytes = (size_t)B * T * NP * sizeof(float);
  if (ws_size >= cost_bytes) {
    float* cost = (float*)d_ws;
    cost_kernel<<<dim3((NP + 255) / 256, B), 256, 0, stream>>>(outputs, targets, cost);
    hungarian_kernel<true><<<B, 64, 0, stream>>>(outputs, targets, cost, out);
  } else {
    hungarian_kernel<false><<<B, 64, 0, stream>>>(outputs, targets, nullptr, out);
  }
}

// Round 13
// 173.514 us; speedup vs baseline: 2.1850x; 2.1850x over previous
//
#include <hip/hip_runtime.h>

namespace {
constexpr int B = 16;
constexpr int N = 900;   // queries (columns)
constexpr int NP = 960;  // padded cost-row stride (floats)
constexpr int T = 64;    // targets (rows)
constexpr int L = 96;
constexpr int CACHE = 38;  // rows cached in LDS: 38*960*4 = 145,920 B
constexpr float BIGF = 1e9f;
}

// Faithful reproduction of the reference cost, FP-contract off to match numpy
__device__ __forceinline__ float cost_elem(float cx, float cy, float w, float h,
                                           float prob,
                                           float tx0, float ty0, float tx1, float ty1) {
#pragma clang fp contract(off)
  float hw = w * 0.5f, hh = h * 0.5f;
  float x0 = cx - hw, y0 = cy - hh;
  float x1 = cx + hw, y1 = cy + hh;
  float cb = fabsf(cx - tx0);
  cb = cb + fabsf(cy - ty0);
  cb = cb + fabsf(w - tx1);
  cb = cb + fabsf(h - ty1);
  float area1 = (x1 - x0) * (y1 - y0);
  float area2 = (tx1 - tx0) * (ty1 - ty0);
  float iw = fmaxf(fminf(x1, tx1) - fmaxf(x0, tx0), 0.0f);
  float ih = fmaxf(fminf(y1, ty1) - fmaxf(y0, ty0), 0.0f);
  float inter = iw * ih;
  float uni = (area1 + area2) - inter;
  float iou = inter / uni;
  float ew = fmaxf(fmaxf(x1, tx1) - fminf(x0, tx0), 0.0f);
  float eh = fmaxf(fmaxf(y1, ty1) - fminf(y0, ty0), 0.0f);
  float ae = ew * eh;
  float giou = iou - (ae - uni) / ae;
  float c = cb * 5.0f;
  c = c + giou * (-2.0f);
  c = c - prob;
  return c;
}

// Covers padded columns [900,960) with BIGF so the solver needs no bounds masks.
__global__ __launch_bounds__(256) void cost_kernel(const float* __restrict__ outputs,
                                                   const float* __restrict__ targets,
                                                   float* __restrict__ cost) {
  __shared__ float tb[T * 4];
  __shared__ int tc[T];
  int b = blockIdx.y;
  int tid = threadIdx.x;
  if (tid < T) {
    const float* tr = targets + (size_t)(b * T + tid) * 5;
    tb[tid * 4 + 0] = tr[0];
    tb[tid * 4 + 1] = tr[1];
    tb[tid * 4 + 2] = tr[2];
    tb[tid * 4 + 3] = tr[3];
    tc[tid] = (int)tr[4];
  }
  __syncthreads();
  int n = blockIdx.x * 256 + tid;
  if (n >= NP) return;
  float* cbase = cost + (size_t)b * T * NP + n;
  if (n >= N) {
    for (int t = 0; t < T; ++t) cbase[(size_t)t * NP] = BIGF;
    return;
  }
  const float* orow = outputs + (size_t)(b * N + n) * L;
  float4 box = *reinterpret_cast<const float4*>(orow);
  for (int t = 0; t < T; ++t) {
    float pc = orow[5 + tc[t]];
    float c = cost_elem(box.x, box.y, box.z, box.w, pc,
                        tb[t * 4 + 0], tb[t * 4 + 1], tb[t * 4 + 2], tb[t * 4 + 3]);
    cbase[(size_t)t * NP] = c;
  }
}

// 64-bit lexicographic min step via DPP (hi = ordered float key, lo = packed j|way).
template <int CTRL>
__device__ __forceinline__ void dpp_step64(unsigned& hi, unsigned& lo) {
  unsigned h2 = (unsigned)__builtin_amdgcn_update_dpp((int)hi, (int)hi, CTRL, 0xf, 0xf, false);
  unsigned l2 = (unsigned)__builtin_amdgcn_update_dpp((int)lo, (int)lo, CTRL, 0xf, 0xf, false);
  unsigned long long a = ((unsigned long long)h2 << 32) | l2;
  unsigned long long cur = ((unsigned long long)hi << 32) | lo;
  bool take = a < cur;
  hi = take ? h2 : hi;
  lo = take ? l2 : lo;
}

__device__ __forceinline__ void wave_min64(unsigned& hi, unsigned& lo) {
  dpp_step64<0x111>(hi, lo);  // row_shr:1
  dpp_step64<0x112>(hi, lo);  // row_shr:2
  dpp_step64<0x114>(hi, lo);  // row_shr:4
  dpp_step64<0x118>(hi, lo);  // row_shr:8
  dpp_step64<0x142>(hi, lo);  // row_bcast:15
  dpp_step64<0x143>(hi, lo);  // row_bcast:31 -> lane 63 holds result
}

// One wave per batch. JV shortest-augmenting-path, bit-faithful to reference.
// Column mapping: 0-based col n0 = 256*k4 + 4*lane + cc, slot e = 4*k4+cc (j ascending in e).
template <bool PRECOMP>
__global__ __launch_bounds__(64) void hungarian_kernel(const float* __restrict__ outputs,
                                                       const float* __restrict__ targets,
                                                       const float* __restrict__ cost,
                                                       int* __restrict__ out) {
  __shared__ float row_cache[CACHE * NP];  // rows 0..CACHE-1, filled at their row-step
  __shared__ int p_lds[N + 1];
  __shared__ int way_lds[N + 1];
  __shared__ int qq[T];
  __shared__ float tb[T * 4];
  __shared__ int tc[T];

  int b = blockIdx.x;
  int lane = threadIdx.x;

  for (int j = lane; j <= N; j += 64) p_lds[j] = 0;
  if (!PRECOMP) {
    const float* tr = targets + (size_t)(b * T + lane) * 5;
    tb[lane * 4 + 0] = tr[0];
    tb[lane * 4 + 1] = tr[1];
    tb[lane * 4 + 2] = tr[2];
    tb[lane * 4 + 3] = tr[3];
    tc[lane] = (int)tr[4];
  }

  float u_reg = 0.0f;  // u[lane+1]
  float v[16], minv[16], uf[16];
  unsigned pk[16];
#pragma unroll
  for (int e = 0; e < 16; ++e) v[e] = 0.0f;

  const float* cost_b = PRECOMP ? (cost + (size_t)b * T * NP) : nullptr;
  const float* obase = outputs + (size_t)b * N * L;
  int lane12 = lane << 12;

  int idx4[4];  // clamped within-row float offsets (pads hold BIGF)
#pragma unroll
  for (int k4 = 0; k4 < 4; ++k4) {
    int idx = (k4 << 8) + (lane << 2);
    idx4[k4] = idx > (NP - 4) ? (NP - 4) : idx;
  }

  float4 c4[4];
  auto load_global = [&](int trow) {
    const float* crow = cost_b + (size_t)trow * NP;
#pragma unroll
    for (int k4 = 0; k4 < 4; ++k4)
      c4[k4] = *reinterpret_cast<const float4*>(crow + idx4[k4]);
  };
  auto load_cached = [&](int trow) {  // mid-path rows: always already filled
    if (trow < CACHE) {
      const float* crow = row_cache + trow * NP;
#pragma unroll
      for (int k4 = 0; k4 < 4; ++k4)
        c4[k4] = *reinterpret_cast<const float4*>(crow + idx4[k4]);
    } else {
      load_global(trow);
    }
  };
  auto gen_row = [&](int trow) {  // !PRECOMP fallback: recompute costs
    float tx0 = tb[trow * 4 + 0], ty0 = tb[trow * 4 + 1];
    float tx1 = tb[trow * 4 + 2], ty1 = tb[trow * 4 + 3];
    int cls = tc[trow];
#pragma unroll
    for (int k4 = 0; k4 < 4; ++k4) {
      float tmp[4];
#pragma unroll
      for (int cc = 0; cc < 4; ++cc) {
        int n0 = (k4 << 8) + (lane << 2) + cc;
        if (n0 < N) {
          const float* orow = obase + (size_t)n0 * L;
          float4 box = *reinterpret_cast<const float4*>(orow);
          float pc = orow[5 + cls];
          tmp[cc] = cost_elem(box.x, box.y, box.z, box.w, pc, tx0, ty0, tx1, ty1);
        } else {
          tmp[cc] = BIGF;
        }
      }
      c4[k4] = make_float4(tmp[0], tmp[1], tmp[2], tmp[3]);
    }
  };

  __syncthreads();
  if (PRECOMP) load_global(0); else gen_row(0);  // row 0 in flight for row-step 1

  for (int i = 1; i <= T; ++i) {
    // fill LDS cache with row i-1 (currently in c4) — off critical path
    if (PRECOMP && (i - 1) < CACHE) {
      float* crow = row_cache + (i - 1) * NP;
#pragma unroll
      for (int k4 = 0; k4 < 4; ++k4)
        *reinterpret_cast<float4*>(crow + idx4[k4]) = c4[k4];
    }
#pragma unroll
    for (int e = 0; e < 16; ++e) {
      minv[e] = BIGF;
      uf[e] = 0.0f;
      pk[e] = 0u;
    }
    int j0s = 0;
    float ui0 = __int_as_float(__builtin_amdgcn_readlane(__float_as_int(u_reg), i - 1));
    bool vis = (lane == i - 1);

    for (int guard = 0; guard <= T + 3; ++guard) {
      // --- candidate scan: reference-exact cur for unused (uf=0); used pushed +BIGF ---
#pragma unroll
      for (int k4 = 0; k4 < 4; ++k4) {
#pragma unroll
        for (int cc = 0; cc < 4; ++cc) {
          int e = (k4 << 2) | cc;
          float cur = ((&c4[k4].x)[cc] - ui0) - v[e];
          cur = fmaf(uf[e], BIGF, cur);
          unsigned pknew = (unsigned)(lane12 + (((k4 << 8) + cc + 1) << 10)) | (unsigned)j0s;
          bool imp = cur < minv[e];
          minv[e] = imp ? cur : minv[e];
          pk[e] = imp ? pknew : pk[e];
        }
      }
      // --- ordered-int keypack + depth-4 u64 lexicographic tree ---
      unsigned kh[16], kl[16];
#pragma unroll
      for (int e = 0; e < 16; ++e) {
        int mi = __float_as_int(minv[e]);
        int s = mi >> 31;
        kh[e] = (unsigned)(mi ^ (s | 0x80000000));
        kl[e] = pk[e];
      }
#pragma unroll
      for (int st = 1; st < 16; st <<= 1) {
#pragma unroll
        for (int e = 0; e < 16; e += (st << 1)) {
          unsigned long long a = ((unsigned long long)kh[e + st] << 32) | kl[e + st];
          unsigned long long cu = ((unsigned long long)kh[e] << 32) | kl[e];
          bool t2 = a < cu;
          kh[e] = t2 ? kh[e + st] : kh[e];
          kl[e] = t2 ? kl[e + st] : kl[e];
        }
      }
      // per-lane gather of p[candidate] BEFORE the DPP chain (latency hides under it)
      int bj = (int)(kl[0] >> 10);
      int bp_g = p_lds[bj <= N ? bj : N];
      unsigned hi = kh[0], lo = kl[0];
      wave_min64(hi, lo);
      unsigned khi = (unsigned)__builtin_amdgcn_readlane((int)hi, 63);
      unsigned klo = (unsigned)__builtin_amdgcn_readlane((int)lo, 63);
      int mbits = (khi & 0x80000000u) ? (int)(khi ^ 0x80000000u) : (int)(~khi);
      float delta = __int_as_float(mbits);
      int j1 = (int)(klo >> 10);
      int w1 = (int)(klo & 1023u);
      int jj = j1 - 1;
      int o1 = (jj >> 2) & 63;
      int e1 = ((jj >> 8) << 2) | (jj & 3);
      int p1 = __builtin_amdgcn_readlane(bp_g, o1);  // winner lane's gathered p[j1]

      if (lane == 0) way_lds[j1] = w1;  // single uniform write per iteration
      if (p1 != 0) {                    // next row's data in flight ASAP
        if (PRECOMP) load_cached(p1 - 1); else gen_row(p1 - 1);
      }

      // --- reference-exact potential updates (registers only, branchless) ---
      if (vis) u_reg += delta;
#pragma unroll
      for (int e = 0; e < 16; ++e) {
        minv[e] = fmaf(uf[e], delta, minv[e] - delta);  // unused: exact minv-delta
        v[e] = fmaf(uf[e], -delta, v[e]);               // used: exact v-delta
      }
      vis = vis || (lane == p1 - 1);

      // --- mark j1 used: pure cndmask, no branches ---
      {
        bool onlane = (lane == o1);
#pragma unroll
        for (int e = 0; e < 16; ++e) {
          bool hit = onlane && (e == e1);
          minv[e] = hit ? BIGF : minv[e];
          uf[e] = hit ? 1.0f : uf[e];
        }
      }

      ui0 = __int_as_float(
          __builtin_amdgcn_readlane(__float_as_int(u_reg), p1 > 0 ? p1 - 1 : 0));
      j0s = j1;
      if (p1 == 0) break;
    }

    // prefetch next row-step's first row (not yet cached -> global); hides under augment
    if (i < T) {
      if (PRECOMP) load_global(i); else gen_row(i);
    }

    // augment along way[] chain (uniform LDS walk; lane 0 writes)
    int jc = j0s;
    for (int g2 = 0; g2 <= T + 3 && jc != 0; ++g2) {
      int jn = way_lds[jc];
      int pv = (jn == 0) ? i : p_lds[jn];
      if (lane == 0) p_lds[jc] = pv;
      jc = jn;
    }
  }

  __syncthreads();
  // extract q: p[j] = row assigned to column j (1-indexed)
  for (int j = 1 + lane; j <= N; j += 64) {
    int r = p_lds[j];
    if (r > 0) qq[r - 1] = j - 1;
  }
  __syncthreads();
  // sort pairs by query index: rank of q_t among all q (distinct values)
  int qt = qq[lane];
  int rank = 0;
  for (int s = 0; s < T; ++s) rank += (qq[s] < qt) ? 1 : 0;
  out[b * T + rank] = qt;            // i_idx (sorted query indices)
  out[B * T + b * T + rank] = lane;  // j_idx (target per sorted position)
}

extern "C" void kernel_launch(void* const* d_in, const int* in_sizes, int n_in,
                              void* d_out, int out_size, void* d_ws, size_t ws_size,
                              hipStream_t stream) {
  const float* outputs = (const float*)d_in[0];
  const float* targets = (const float*)d_in[1];
  int* out = (int*)d_out;

  size_t cost_bytes = (size_t)B * T * NP * sizeof(float);
  if (ws_size >= cost_bytes) {
    float* cost = (float*)d_ws;
    cost_kernel<<<dim3((NP + 255) / 256, B), 256, 0, stream>>>(outputs, targets, cost);
    hungarian_kernel<true><<<B, 64, 0, stream>>>(outputs, targets, cost, out);
  } else {
    hungarian_kernel<false><<<B, 64, 0, stream>>>(outputs, targets, nullptr, out);
  }
}